// Round 6
// baseline (490.990 us; speedup 1.0000x reference)
//
#include <hip/hip_runtime.h>
#include <hip/hip_bf16.h>

// Problem constants
// inputs [512][4][124][124], conv1 w[32][4][8][8] s4 -> [512][32][30][30] (bf16, MFMA)
// conv2 w[64][32][4][4] s2 -> [512][64][14][14] bf16  (MFMA, full-image LDS staging)
// conv3 w[32][64][3][3] s1 -> [512][32][12][12] bf16  (MFMA, channel-last LDS)
// fc [512,4608] -> xs [512][512] relu  (MFMA, split-K x4 + reduce)
// gi = xs @ w_ih^T + b_ih : [512][1536]  (MFMA, bf16x2 split for fp32 accuracy)
// GRU T=32, N=16, H=512 ; heads A=6
// d_out: value[512] | alp[512] | ent[512] | states_out[16*512]

typedef __bf16 bf16x8_t __attribute__((ext_vector_type(8)));
typedef float  f32x4_t  __attribute__((ext_vector_type(4)));

__device__ __forceinline__ unsigned int pack_bf2(float a, float b) {
  union { __bf16 h[2]; unsigned int u; } c;
  c.h[0] = (__bf16)a; c.h[1] = (__bf16)b;
  return c.u;
}
__device__ __forceinline__ unsigned short f2bf(float x) {
  union { __bf16 h; unsigned short s; } c; c.h = (__bf16)x; return c.s;
}
// fast sigmoid/tanh: v_exp + v_rcp (~1 ulp each; abs tol is 7.8e-3)
__device__ __forceinline__ float fsig(float x) {
  return __builtin_amdgcn_rcpf(1.f + __expf(-x));
}
__device__ __forceinline__ float ftanh_f(float x) {
  float e = __expf(2.f * x);
  return 1.f - 2.f * __builtin_amdgcn_rcpf(e + 1.f);
}

// ---------------- conv1 v2: slab-staged bf16 MFMA, no im2col ----------------
__global__ __launch_bounds__(256, 2) void conv1_mfma(const float* __restrict__ x,
        const float* __restrict__ w, const float* __restrict__ bias,
        unsigned short* __restrict__ out) {
  __shared__ __align__(16) unsigned short img[4*64*140];   // 71.7 KB
  const int tid  = threadIdx.x;
  const int lane = tid & 63;
  const int wv   = tid >> 6;
  const int n    = blockIdx.x >> 1;
  const int half = blockIdx.x & 1;
  const int y0   = half * 60;
  {
    #pragma unroll
    for (int it = 0; it < 31; ++it) {
      int i  = it*256 + tid;          // [0, 4*64*31)
      int c  = i / 1984;
      int r  = i - c*1984;
      int y  = r / 31;
      int xq = r - y*31;
      const float4 f = *(const float4*)(x + ((size_t)(n*4 + c)*124 + (y0 + y))*124 + xq*4);
      uint2 v; v.x = pack_bf2(f.x, f.y); v.y = pack_bf2(f.z, f.w);
      *(uint2*)&img[(c*64 + y)*140 + xq*4] = v;
    }
  }
  bf16x8_t wfr[2][8];
  {
    int m = lane & 15, q = lane >> 4;
    #pragma unroll
    for (int tt = 0; tt < 2; ++tt) {
      const float* wrow = w + (size_t)(tt*16 + m)*256 + q*8;
      #pragma unroll
      for (int ks = 0; ks < 8; ++ks) {
        float4 f0 = *(const float4*)(wrow + ks*32);
        float4 f1 = *(const float4*)(wrow + ks*32 + 4);
        bf16x8_t v;
        v[0]=(__bf16)f0.x; v[1]=(__bf16)f0.y; v[2]=(__bf16)f0.z; v[3]=(__bf16)f0.w;
        v[4]=(__bf16)f1.x; v[5]=(__bf16)f1.y; v[6]=(__bf16)f1.z; v[7]=(__bf16)f1.w;
        wfr[tt][ks] = v;
      }
    }
  }
  __syncthreads();
  const int m = lane & 15, q = lane >> 4;
  int rb[8];
  #pragma unroll
  for (int ks = 0; ks < 8; ++ks) {
    int kk = ks*32 + q*8;
    rb[ks] = (kk >> 6)*64 + ((kk >> 3) & 7);
  }
  const float sc = 1.0f / 255.0f;
  for (int tile = wv; tile < 29; tile += 4) {
    int pl = tile*16 + m;
    int ok = pl < 450;
    if (!ok) pl = 449;
    int t = pl / 30, opx = pl - t*30;
    int t4 = t*4, opx4 = opx*4;
    f32x4_t acc0 = {0.f,0.f,0.f,0.f}, acc1 = {0.f,0.f,0.f,0.f};
    #pragma unroll
    for (int ks = 0; ks < 8; ++ks) {
      const unsigned short* p = &img[(rb[ks] + t4)*140 + opx4];
      union { bf16x8_t v; uint2 u[2]; } fb;
      fb.u[0] = *(const uint2*)p;
      fb.u[1] = *(const uint2*)(p + 4);
      acc0 = __builtin_amdgcn_mfma_f32_16x16x32_bf16(wfr[0][ks], fb.v, acc0, 0, 0, 0);
      acc1 = __builtin_amdgcn_mfma_f32_16x16x32_bf16(wfr[1][ks], fb.v, acc1, 0, 0, 0);
    }
    if (ok) {
      int opy = half*15 + t;
      size_t obase = (size_t)n*32*900 + opy*30 + opx;
      #pragma unroll
      for (int rg = 0; rg < 4; ++rg) {
        int oc0 = q*4 + rg;
        out[obase + (size_t)oc0*900]      = f2bf(fmaxf(acc0[rg]*sc + bias[oc0], 0.f));
        out[obase + (size_t)(oc0+16)*900] = f2bf(fmaxf(acc1[rg]*sc + bias[oc0+16], 0.f));
      }
    }
  }
}

// ---------------- conv2 v2: full-image LDS staging, bf16 output ----------------
__global__ __launch_bounds__(256, 2) void conv2_mfma(const unsigned short* __restrict__ in,
        const float* __restrict__ w, const float* __restrict__ bias,
        unsigned short* __restrict__ out) {
  __shared__ __align__(16) unsigned short img[28800];   // [c][y][x] linear, 57.6 KB
  const int tid  = threadIdx.x;
  const int lane = tid & 63;
  const int wv   = tid >> 6;
  const int n    = blockIdx.x;
  {
    const uint4* src = (const uint4*)(in + (size_t)n*28800);
    uint4* dst = (uint4*)img;
    #pragma unroll
    for (int j = 0; j < 15; ++j) {
      int s = j*256 + tid;
      if (s < 3600) dst[s] = src[s];
    }
  }
  bf16x8_t wfr[16];
  {
    int m = lane & 15, q = lane >> 4;
    const float* wrow = w + (size_t)(wv*16 + m)*512 + q*8;
    #pragma unroll
    for (int ks = 0; ks < 16; ++ks) {
      float4 f0 = *(const float4*)(wrow + ks*32);
      float4 f1 = *(const float4*)(wrow + ks*32 + 4);
      bf16x8_t v;
      v[0] = (__bf16)f0.x; v[1] = (__bf16)f0.y; v[2] = (__bf16)f0.z; v[3] = (__bf16)f0.w;
      v[4] = (__bf16)f1.x; v[5] = (__bf16)f1.y; v[6] = (__bf16)f1.z; v[7] = (__bf16)f1.w;
      wfr[ks] = v;
    }
  }
  __syncthreads();
  const int m  = lane & 15;
  const int qq = lane >> 4;
  const int cl  = qq >> 1;            // channel offset within 2-ch k-step
  const int ky0 = (qq & 1) * 2;       // row offset
  float b4[4];
  #pragma unroll
  for (int rg = 0; rg < 4; ++rg) b4[rg] = bias[wv*16 + qq*4 + rg];
  for (int tile = 0; tile < 13; ++tile) {
    int px = tile*16 + m;
    int valid = px < 196;
    int pc = valid ? px : 195;
    int oy = pc / 14, ox = pc % 14;
    const unsigned short* pb = &img[((cl*30) + oy*2 + ky0)*30 + ox*2];
    f32x4_t acc = {0.f, 0.f, 0.f, 0.f};
    #pragma unroll
    for (int ks = 0; ks < 16; ++ks) {
      const unsigned short* p0 = pb + ks*1800;    // channel 2*ks + cl
      union { bf16x8_t v; unsigned int u[4]; } fb;
      fb.u[0] = *(const unsigned int*)(p0);
      fb.u[1] = *(const unsigned int*)(p0 + 2);
      fb.u[2] = *(const unsigned int*)(p0 + 30);
      fb.u[3] = *(const unsigned int*)(p0 + 32);
      acc = __builtin_amdgcn_mfma_f32_16x16x32_bf16(wfr[ks], fb.v, acc, 0, 0, 0);
    }
    if (valid) {
      #pragma unroll
      for (int rg = 0; rg < 4; ++rg) {
        int oc = wv*16 + qq*4 + rg;
        out[((size_t)n*64 + oc)*196 + px] = f2bf(fmaxf(acc[rg] + b4[rg], 0.f));
      }
    }
  }
}

// ---------------- conv3 v2: bf16 MFMA, channel-last LDS image ----------------
__global__ __launch_bounds__(256) void conv3_mfma(const unsigned short* __restrict__ in,
        const float* __restrict__ w, const float* __restrict__ bias,
        unsigned short* __restrict__ out) {
  __shared__ __align__(16) unsigned short img[196*72];   // 27.6 KB
  const int tid  = threadIdx.x;
  const int lane = tid & 63;
  const int wv   = tid >> 6;
  const int n    = blockIdx.x;
  {
    const unsigned short* src = in + (size_t)n*12544;     // [c][196]
    for (int i = tid; i < 3136; i += 256) {
      int c = i / 49, j = i - c*49;
      uint2 v = *(const uint2*)(src + c*196 + j*4);
      int px = j*4;
      img[(px+0)*72 + c] = (unsigned short)(v.x);
      img[(px+1)*72 + c] = (unsigned short)(v.x >> 16);
      img[(px+2)*72 + c] = (unsigned short)(v.y);
      img[(px+3)*72 + c] = (unsigned short)(v.y >> 16);
    }
  }
  // weights -> A-frags: k = ks*32 + q*8 + e ; g = ks>>1, c = (ks&1)*32 + q*8 + e
  bf16x8_t wfr[2][18];
  {
    int m = lane & 15, q = lane >> 4;
    #pragma unroll
    for (int tt = 0; tt < 2; ++tt) {
      const float* wrow = w + (size_t)(tt*16 + m)*576;
      #pragma unroll
      for (int ks = 0; ks < 18; ++ks) {
        int g = ks >> 1;
        int c0 = (ks & 1)*32 + q*8;
        bf16x8_t v;
        #pragma unroll
        for (int e = 0; e < 8; ++e) v[e] = (__bf16)wrow[(c0 + e)*9 + g];
        wfr[tt][ks] = v;
      }
    }
  }
  __syncthreads();
  const int m = lane & 15, q = lane >> 4;
  for (int tile = wv; tile < 9; tile += 4) {
    int px = tile*16 + m;                 // 0..143 always valid
    int oy = px / 12, ox = px % 12;
    f32x4_t a0 = {0.f,0.f,0.f,0.f}, a1 = {0.f,0.f,0.f,0.f};
    #pragma unroll
    for (int ks = 0; ks < 18; ++ks) {
      int g = ks >> 1, ky = g / 3, kx = g % 3;
      int c0 = (ks & 1)*32 + q*8;
      const unsigned short* p = &img[((oy + ky)*14 + ox + kx)*72 + c0];
      union { bf16x8_t v; uint4 u; } fb;
      fb.u = *(const uint4*)p;
      a0 = __builtin_amdgcn_mfma_f32_16x16x32_bf16(wfr[0][ks], fb.v, a0, 0, 0, 0);
      a1 = __builtin_amdgcn_mfma_f32_16x16x32_bf16(wfr[1][ks], fb.v, a1, 0, 0, 0);
    }
    #pragma unroll
    for (int rg = 0; rg < 4; ++rg) {
      int oc = q*4 + rg;
      out[((size_t)n*32 + oc)*144 + px]      = f2bf(fmaxf(a0[rg] + bias[oc], 0.f));
      out[((size_t)n*32 + oc + 16)*144 + px] = f2bf(fmaxf(a1[rg] + bias[oc + 16], 0.f));
    }
  }
}

// ---------------- W fp32 -> bf16 one-shot convert (+ flags zero) ----------------
__global__ __launch_bounds__(256) void cvt_w_k(const float* __restrict__ w,
        unsigned short* __restrict__ o, int* __restrict__ flags) {
  if (blockIdx.x == 0) ((int4*)flags)[threadIdx.x] = make_int4(0, 0, 0, 0);  // 4 KB
  int i = (blockIdx.x*256 + threadIdx.x) * 8;
  float4 f0 = *(const float4*)(w + i);
  float4 f1 = *(const float4*)(w + i + 4);
  uint4 v;
  v.x = pack_bf2(f0.x, f0.y); v.y = pack_bf2(f0.z, f0.w);
  v.z = pack_bf2(f1.x, f1.y); v.w = pack_bf2(f1.z, f1.w);
  *(uint4*)(o + i) = v;
}

// ---------------- fc: bf16 MFMA GEMM, split-K x4 -> fp32 partials ----------------
__global__ __launch_bounds__(256) void fc_mfma(const unsigned short* __restrict__ A,
        const unsigned short* __restrict__ Wb, float* __restrict__ part) {
  __shared__ __align__(16) unsigned short As[64*72];
  __shared__ __align__(16) unsigned short Wsm[64*72];
  const int tid  = threadIdx.x;
  const int lane = tid & 63;
  const int wv   = tid >> 6;
  const int m0 = blockIdx.y * 64, n0 = blockIdx.x * 64;
  const int kz = blockIdx.z * 1152;
  const int r  = tid >> 2;
  const int cq = (tid & 3) * 16;
  f32x4_t acc[4] = {{0,0,0,0},{0,0,0,0},{0,0,0,0},{0,0,0,0}};
  for (int k0 = 0; k0 < 1152; k0 += 64) {
    __syncthreads();
    {
      const uint4* src = (const uint4*)(A + (size_t)(m0 + r)*4608 + kz + k0 + cq);
      uint4 a0 = src[0], a1 = src[1];
      *(uint4*)&As[r*72 + cq]     = a0;
      *(uint4*)&As[r*72 + cq + 8] = a1;
    }
    {
      const uint4* src = (const uint4*)(Wb + (size_t)(n0 + r)*4608 + kz + k0 + cq);
      uint4 w0 = src[0], w1 = src[1];
      *(uint4*)&Wsm[r*72 + cq]     = w0;
      *(uint4*)&Wsm[r*72 + cq + 8] = w1;
    }
    __syncthreads();
    #pragma unroll
    for (int kk = 0; kk < 2; ++kk) {
      union { bf16x8_t v; uint4 u; } bf;
      bf.u = *(const uint4*)&As[(wv*16 + (lane & 15))*72 + kk*32 + (lane >> 4)*8];
      #pragma unroll
      for (int tt = 0; tt < 4; ++tt) {
        union { bf16x8_t v; uint4 u; } af;
        af.u = *(const uint4*)&Wsm[(tt*16 + (lane & 15))*72 + kk*32 + (lane >> 4)*8];
        acc[tt] = __builtin_amdgcn_mfma_f32_16x16x32_bf16(af.v, bf.v, acc[tt], 0, 0, 0);
      }
    }
  }
  {
    int m = m0 + wv*16 + (lane & 15);
    int q4 = lane >> 4;
    float* dst = part + (size_t)blockIdx.z*262144;
    #pragma unroll
    for (int tt = 0; tt < 4; ++tt) {
      #pragma unroll
      for (int rg = 0; rg < 4; ++rg) {
        int n = n0 + tt*16 + q4*4 + rg;
        dst[(size_t)m*512 + n] = acc[tt][rg];
      }
    }
  }
}

// ---------------- fc reduce: xs = relu(sum_z part + bias) ----------------
__global__ __launch_bounds__(256) void fc_red(const float* __restrict__ part,
        const float* __restrict__ bias, float* __restrict__ C) {
  int idx = blockIdx.x*256 + threadIdx.x;      // 0..65535 float4s
  int nq = idx & 127;
  const float4* p = (const float4*)part;
  float4 s0 = p[idx];
  float4 s1 = p[65536 + idx];
  float4 s2 = p[131072 + idx];
  float4 s3 = p[196608 + idx];
  float4 b = *(const float4*)(bias + nq*4);
  float4 r;
  r.x = fmaxf(s0.x + s1.x + s2.x + s3.x + b.x, 0.f);
  r.y = fmaxf(s0.y + s1.y + s2.y + s3.y + b.y, 0.f);
  r.z = fmaxf(s0.z + s1.z + s2.z + s3.z + b.z, 0.f);
  r.w = fmaxf(s0.w + s1.w + s2.w + s3.w + b.w, 0.f);
  ((float4*)C)[idx] = r;
}

// ---------------- gi: bf16x2 split-precision MFMA GEMM ----------------
__global__ __launch_bounds__(256) void gi_mfma(const float* __restrict__ A,
        const float* __restrict__ W, const float* __restrict__ bias,
        float* __restrict__ C) {
  __shared__ __align__(16) unsigned short Ash[64*72], Asl[64*72];
  __shared__ __align__(16) unsigned short Wsh[64*72], Wsl[64*72];
  const int tid  = threadIdx.x;
  const int lane = tid & 63;
  const int wv   = tid >> 6;
  const int m0 = blockIdx.y * 64, n0 = blockIdx.x * 64;
  const int r  = tid >> 2;
  const int cq = (tid & 3) * 16;
  f32x4_t acc[4] = {{0,0,0,0},{0,0,0,0},{0,0,0,0},{0,0,0,0}};
  for (int k0 = 0; k0 < 512; k0 += 64) {
    __syncthreads();
    #pragma unroll
    for (int op = 0; op < 2; ++op) {
      const float* src = (op ? W + (size_t)(n0 + r)*512 : A + (size_t)(m0 + r)*512) + k0 + cq;
      unsigned short* dh = (op ? Wsh : Ash) + r*72 + cq;
      unsigned short* dl = (op ? Wsl : Asl) + r*72 + cq;
      #pragma unroll
      for (int hb = 0; hb < 2; ++hb) {
        float4 f0 = *(const float4*)(src + hb*8);
        float4 f1 = *(const float4*)(src + hb*8 + 4);
        float v[8] = {f0.x,f0.y,f0.z,f0.w,f1.x,f1.y,f1.z,f1.w};
        uint4 vh, vl;
        unsigned int* ph = (unsigned int*)&vh;
        unsigned int* pl = (unsigned int*)&vl;
        #pragma unroll
        for (int e = 0; e < 4; ++e) {
          float a = v[e*2], b = v[e*2+1];
          __bf16 ah = (__bf16)a, bh = (__bf16)b;
          union { __bf16 h[2]; unsigned int u; } ch, clo;
          ch.h[0] = ah; ch.h[1] = bh;
          clo.h[0] = (__bf16)(a - (float)ah); clo.h[1] = (__bf16)(b - (float)bh);
          ph[e] = ch.u; pl[e] = clo.u;
        }
        *(uint4*)(dh + hb*8) = vh;
        *(uint4*)(dl + hb*8) = vl;
      }
    }
    __syncthreads();
    #pragma unroll
    for (int kk = 0; kk < 2; ++kk) {
      int boff = (wv*16 + (lane & 15))*72 + kk*32 + (lane >> 4)*8;
      union { bf16x8_t v; uint4 u; } bh, bl;
      bh.u = *(const uint4*)&Ash[boff];
      bl.u = *(const uint4*)&Asl[boff];
      #pragma unroll
      for (int tt = 0; tt < 4; ++tt) {
        int aoff = (tt*16 + (lane & 15))*72 + kk*32 + (lane >> 4)*8;
        union { bf16x8_t v; uint4 u; } ah, al;
        ah.u = *(const uint4*)&Wsh[aoff];
        al.u = *(const uint4*)&Wsl[aoff];
        acc[tt] = __builtin_amdgcn_mfma_f32_16x16x32_bf16(ah.v, bh.v, acc[tt], 0, 0, 0);
        acc[tt] = __builtin_amdgcn_mfma_f32_16x16x32_bf16(ah.v, bl.v, acc[tt], 0, 0, 0);
        acc[tt] = __builtin_amdgcn_mfma_f32_16x16x32_bf16(al.v, bh.v, acc[tt], 0, 0, 0);
      }
    }
  }
  {
    int m = m0 + wv*16 + (lane & 15);
    int q4 = lane >> 4;
    #pragma unroll
    for (int tt = 0; tt < 4; ++tt) {
      #pragma unroll
      for (int rg = 0; rg < 4; ++rg) {
        int n = n0 + tt*16 + q4*4 + rg;
        C[(size_t)m*1536 + n] = acc[tt][rg] + bias[n];
      }
    }
  }
}

// ---------------- GRU persistent kernel v11: per-wave flags + wave-specialized copy ----------------
// v9's publish path serialized: block barrier (drain all 8 waves) -> tid0 flag ->
// peers poll -> bulk copy. v11: wave wv's 64 publish words are exactly slice words
// [wv*64, wv*64+64), so each wave drains ITS OWN stores (s_waitcnt vmcnt(0), no
// barrier) and sets flag (b,wv). Reader wave w needs only words [w*64, w*64+64) of
// each peer = written by the peer's wave w (symmetric timing): poll 7 flags (p,w)
// via lanes 0-6, then issue all 7 data loads at once (1 u32/lane/peer, one RTT).
// WAR on hbf still protected by the post-MFMA barrier; parity double-buffer
// argument unchanged (flag(p,w)>=t => peer wave finished copying tag t-1).
#define GRU_NB 8
__global__ __launch_bounds__(512) void gru_k(const float* __restrict__ gi, const float* __restrict__ states,
    const float* __restrict__ masks, const float* __restrict__ w_hh, const float* __restrict__ b_hh,
    float* __restrict__ outs, unsigned int* __restrict__ hbuf, int* __restrict__ flags,
    float* __restrict__ states_out) {
  __shared__ __align__(16) unsigned short hbf[16*520];
  __shared__ float hp_s[16*64];
  __shared__ float gh_s[192*17];
  __shared__ float bhs[192];
  __shared__ float mask_s[512];
  const int b    = blockIdx.x;
  const int tid  = threadIdx.x;
  const int lane = tid & 63;
  const int wv   = tid >> 6;          // 0..7
  const int jbase = b * 64;
  const int gn = tid >> 5;            // batch row 0..15  (wave wv -> rows {2wv, 2wv+1})
  const int gj = (tid & 31) * 2;      // adjacent j-pair 0..62

  mask_s[tid < 512 ? tid : 0] = masks[tid < 512 ? tid : 0];
  if (tid < 192) bhs[tid] = b_hh[(tid >> 6)*512 + jbase + (tid & 63)];

  bf16x8_t wfr[2][16];
  {
    int r = lane & 15, q = lane >> 4;
    #pragma unroll
    for (int ti = 0; ti < 2; ++ti) {
      int tt = wv + ti*8;
      if (tt < 12) {
        int g = tt >> 2, jt = (tt & 3) * 16;
        const float* wrow = w_hh + (size_t)(g*512 + jbase + jt + r)*512 + q*8;
        #pragma unroll
        for (int ks = 0; ks < 16; ++ks) {
          float4 f0 = *(const float4*)(wrow + ks*32);
          float4 f1 = *(const float4*)(wrow + ks*32 + 4);
          bf16x8_t v;
          v[0] = (__bf16)f0.x; v[1] = (__bf16)f0.y; v[2] = (__bf16)f0.z; v[3] = (__bf16)f0.w;
          v[4] = (__bf16)f1.x; v[5] = (__bf16)f1.y; v[6] = (__bf16)f1.z; v[7] = (__bf16)f1.w;
          wfr[ti][ks] = v;
        }
      }
    }
  }
  __syncthreads();

  for (int t = 0; t < 32; ++t) {
    const float* gip = gi + (size_t)(t*16 + gn)*1536 + jbase + gj;
    float2 giR = *(const float2*)(gip);
    float2 giZ = *(const float2*)(gip + 512);
    float2 giN = *(const float2*)(gip + 1024);

    if (t == 0) {
      for (int i = tid; i < 4096; i += 512) {
        int nn = i >> 8, kp = (i & 255) * 2;
        float m = mask_s[nn];
        float f0 = states[nn*512 + kp], f1 = states[nn*512 + kp + 1];
        *(unsigned int*)&hbf[nn*520 + kp] = pack_bf2(f0*m, f1*m);
      }
      {
        float m0 = mask_s[gn];
        hp_s[gn*64 + gj]     = states[gn*512 + jbase + gj] * m0;
        hp_s[gn*64 + gj + 1] = states[gn*512 + jbase + gj + 1] * m0;
      }
      __syncthreads();
    } else {
      // wave wv waits for peer-wave flags (p, wv), p != b   (lanes 0..6)
      {
        int done = 0;
        while (!done) {
          int ok = 1;
          if (lane < 7) {
            int p = lane + (lane >= b);
            int v = __hip_atomic_load(&flags[(p*8 + wv)*16], __ATOMIC_RELAXED, __HIP_MEMORY_SCOPE_AGENT);
            ok = (v >= t);
          }
          done = __all(ok);
          if (!done) __builtin_amdgcn_s_sleep(1);
        }
      }
      // copy: word range [wv*64, wv*64+64) of each of the 7 peer slices.
      // 7 independent u32 atomic loads per lane -> one LLC round trip total.
      {
        const unsigned int* hsrc = hbuf + (t & 1)*4096;
        const int gn2 = 2*wv + (lane >> 5);
        const int jw  = lane & 31;
        #pragma unroll
        for (int k = 0; k < 7; ++k) {
          int p = k + (k >= b);
          unsigned int u = __hip_atomic_load(hsrc + p*512 + wv*64 + lane,
                                             __ATOMIC_RELAXED, __HIP_MEMORY_SCOPE_AGENT);
          *(unsigned int*)&hbf[gn2*520 + p*64 + jw*2] = u;
        }
      }
      __syncthreads();
    }

    // MFMA: gh = w_hh(slice) * h
    {
      int r = lane & 15, q = lane >> 4;
      const unsigned short* hrow = &hbf[r*520 + q*8];
      #pragma unroll
      for (int ti = 0; ti < 2; ++ti) {
        int tt = wv + ti*8;
        if (tt < 12) {
          f32x4_t acc = {0.f, 0.f, 0.f, 0.f};
          #pragma unroll
          for (int ks = 0; ks < 16; ++ks) {
            union { bf16x8_t v; uint4 u; } fb;
            fb.u = *(const uint4*)(hrow + ks*32);
            acc = __builtin_amdgcn_mfma_f32_16x16x32_bf16(wfr[ti][ks], fb.v, acc, 0, 0, 0);
          }
          int g = tt >> 2, jt = (tt & 3) * 16;
          #pragma unroll
          for (int rg = 0; rg < 4; ++rg)
            gh_s[(g*64 + jt + q*4 + rg)*17 + r] = acc[rg];
        }
      }
    }
    __syncthreads();   // all MFMA hbf-reads done -> safe to overwrite hbf next step

    // gates: publish -> wave drain -> wave flag -> cold stores
    {
      float ghr0 = gh_s[(gj    )*17 + gn] + bhs[gj];
      float ghr1 = gh_s[(gj + 1)*17 + gn] + bhs[gj + 1];
      float ghz0 = gh_s[(64 + gj)*17 + gn] + bhs[64 + gj];
      float ghz1 = gh_s[(65 + gj)*17 + gn] + bhs[65 + gj];
      float ghn0 = gh_s[(128 + gj)*17 + gn] + bhs[128 + gj];
      float ghn1 = gh_s[(129 + gj)*17 + gn] + bhs[129 + gj];
      float r0 = fsig(giR.x + ghr0);
      float r1 = fsig(giR.y + ghr1);
      float z0 = fsig(giZ.x + ghz0);
      float z1 = fsig(giZ.y + ghz1);
      float n0 = ftanh_f(giN.x + r0*ghn0);
      float n1 = ftanh_f(giN.y + r1*ghn1);
      float hp0 = hp_s[gn*64 + gj];
      float hp1 = hp_s[gn*64 + gj + 1];
      float hn0 = (1.f - z0)*n0 + z0*hp0;
      float hn1 = (1.f - z1)*n1 + z1*hp1;
      if (t < 31) {
        float mnext = mask_s[(t+1)*16 + gn];
        float hm0 = hn0 * mnext, hm1 = hn1 * mnext;
        // critical path: publish word (wave wv's words = [wv*64, wv*64+64))
        __hip_atomic_store(hbuf + ((t+1)&1)*4096 + b*512 + gn*32 + (gj >> 1),
                           pack_bf2(hm0, hm1), __ATOMIC_RELAXED, __HIP_MEMORY_SCOPE_AGENT);
        asm volatile("s_waitcnt vmcnt(0)" ::: "memory");   // wave-local drain
        if (lane == 0)
          __hip_atomic_store(&flags[(b*8 + wv)*16], t + 1, __ATOMIC_RELAXED, __HIP_MEMORY_SCOPE_AGENT);
        // cold stores off the inter-block critical path
        *(float2*)&outs[(size_t)(t*16 + gn)*512 + jbase + gj] = make_float2(hn0, hn1);
        hp_s[gn*64 + gj]     = hm0;
        hp_s[gn*64 + gj + 1] = hm1;
        *(unsigned int*)&hbf[gn*520 + jbase + gj] = pack_bf2(hm0, hm1);
      } else {
        *(float2*)&outs[(size_t)(t*16 + gn)*512 + jbase + gj] = make_float2(hn0, hn1);
        *(float2*)&states_out[gn*512 + jbase + gj] = make_float2(hn0, hn1);
      }
    }
  }
}

// ---------------- heads ----------------
__global__ __launch_bounds__(256) void heads_k(const float* __restrict__ xs, const int* __restrict__ action,
    const float* __restrict__ aw, const float* __restrict__ ab,
    const float* __restrict__ cw, const float* __restrict__ cb, float* __restrict__ out) {
  int row  = blockIdx.x * 4 + (threadIdx.x >> 6);
  int lane = threadIdx.x & 63;
  const float* xr = xs + (size_t)row * 512;
  float acc[7];
  #pragma unroll
  for (int a = 0; a < 7; ++a) acc[a] = 0.f;
  #pragma unroll
  for (int kb = 0; kb < 8; ++kb) {
    int k = kb*64 + lane;
    float xv = xr[k];
    #pragma unroll
    for (int a = 0; a < 6; ++a) acc[a] += xv * aw[a*512 + k];
    acc[6] += xv * cw[k];
  }
  #pragma unroll
  for (int off = 32; off > 0; off >>= 1) {
    #pragma unroll
    for (int a = 0; a < 7; ++a) acc[a] += __shfl_down(acc[a], off);
  }
  if (lane == 0) {
    float lg[6];
    #pragma unroll
    for (int a = 0; a < 6; ++a) lg[a] = acc[a] + ab[a];
    float mx = lg[0];
    #pragma unroll
    for (int a = 1; a < 6; ++a) mx = fmaxf(mx, lg[a]);
    float se = 0.f;
    #pragma unroll
    for (int a = 0; a < 6; ++a) se += expf(lg[a] - mx);
    float lse = mx + logf(se);
    float ent = 0.f;
    #pragma unroll
    for (int a = 0; a < 6; ++a) { float lp = lg[a] - lse; ent -= expf(lp)*lp; }
    int ai = action[row];
    out[row]        = acc[6] + cb[0];
    out[512  + row] = lg[ai] - lse;
    out[1024 + row] = ent;
  }
}

extern "C" void kernel_launch(void* const* d_in, const int* in_sizes, int n_in,
                              void* d_out, int out_size, void* d_ws, size_t ws_size,
                              hipStream_t stream) {
  const float* x      = (const float*)d_in[0];
  const float* states = (const float*)d_in[1];
  const float* masks  = (const float*)d_in[2];
  const int*   action = (const int*)d_in[3];
  const float* c1w = (const float*)d_in[4];
  const float* c1b = (const float*)d_in[5];
  const float* c2w = (const float*)d_in[6];
  const float* c2b = (const float*)d_in[7];
  const float* c3w = (const float*)d_in[8];
  const float* c3b = (const float*)d_in[9];
  const float* fcw = (const float*)d_in[10];
  const float* fcb = (const float*)d_in[11];
  const float* wih = (const float*)d_in[12];
  const float* whh = (const float*)d_in[13];
  const float* bih = (const float*)d_in[14];
  const float* bhh = (const float*)d_in[15];
  const float* aw  = (const float*)d_in[16];
  const float* ab  = (const float*)d_in[17];
  const float* cw  = (const float*)d_in[18];
  const float* cb  = (const float*)d_in[19];
  (void)in_sizes; (void)n_in; (void)out_size; (void)ws_size;

  float* ws = (float*)d_ws;
  // Workspace map (float offsets):
  //   [0, 7372800)        o1b conv1 out bf16 (29.5 MB)  -> later o3b (4.7 MB)
  //   [2359296, 2621440)  xs fp32
  //   [2621440, 3407872)  gibuf
  //   [3407872, 3670016)  outs
  //   [3670016, 3686400)  hbuf ; [3686400, +1024 ints) flags (8 blk x 8 wv x 16)
  //   [7372800, 8552448)  wbf: fc W bf16 (4.7 MB)
  //   [8552448, 9601024)  fc partials 4 x 512 x 512 fp32 (4 MB)
  //   [14745600, ...)     o2b conv2 out bf16 (12.9 MB)
  unsigned short* o1b = (unsigned short*)ws;
  unsigned short* o2b = (unsigned short*)(ws + 14745600);
  unsigned short* o3b = (unsigned short*)ws;
  float* xs    = ws + 2359296;
  float* gibuf = ws + 2621440;
  float* outs  = ws + 3407872;
  unsigned int* hbuf = (unsigned int*)(ws + 3670016);
  int*   flags = (int*)(ws + 3686400);
  unsigned short* wbf = (unsigned short*)(ws + 7372800);
  float* fcpart = ws + 8552448;
  float* out   = (float*)d_out;

  cvt_w_k<<<1152, 256, 0, stream>>>(fcw, wbf, flags);
  conv1_mfma<<<1024, 256, 0, stream>>>(x, c1w, c1b, o1b);
  conv2_mfma<<<512, 256, 0, stream>>>(o1b, c2w, c2b, o2b);
  conv3_mfma<<<512, 256, 0, stream>>>(o2b, c3w, c3b, o3b);
  fc_mfma<<<dim3(8, 8, 4), 256, 0, stream>>>(o3b, wbf, fcpart);
  fc_red<<<256, 256, 0, stream>>>(fcpart, fcb, xs);
  gi_mfma<<<dim3(24, 8), 256, 0, stream>>>(xs, wih, bih, gibuf);
  gru_k<<<GRU_NB, 512, 0, stream>>>(gibuf, states, masks, whh, bhh, outs, hbuf, flags, out + 1536);
  heads_k<<<128, 256, 0, stream>>>(outs, action, aw, ab, cw, cb, out);
}

// Round 8
// 459.800 us; speedup vs baseline: 1.0678x; 1.0678x over previous
//
#include <hip/hip_runtime.h>
#include <hip/hip_bf16.h>

// Problem constants
// inputs [512][4][124][124], conv1 w[32][4][8][8] s4 -> [512][32][30][30] (bf16, MFMA)
// conv2 w[64][32][4][4] s2 -> [512][64][14][14] bf16  (MFMA, full-image LDS staging)
// conv3 w[32][64][3][3] s1 -> [512][32][12][12] bf16  (MFMA, channel-last LDS)
// fc [512,4608] -> xs [512][512] relu  (MFMA, split-K x4 + reduce)
// gi = xs @ w_ih^T + b_ih : [512][1536]  (MFMA, bf16x2 split for fp32 accuracy)
// GRU T=32, N=16, H=512 ; heads A=6
// d_out: value[512] | alp[512] | ent[512] | states_out[16*512]
//
// GRU exchange protocol: v9 (8 blocks x 512 thr, agent-scope flag+bulk-copy) is
// FINAL. v10 (fused tag+data), v11 (per-wave flags), v12 (same-XCD L2 scope)
// all regressed or broke — v9 sits at the platform's inter-block sync latency.

typedef __bf16 bf16x8_t __attribute__((ext_vector_type(8)));
typedef float  f32x4_t  __attribute__((ext_vector_type(4)));

__device__ __forceinline__ unsigned int pack_bf2(float a, float b) {
  union { __bf16 h[2]; unsigned int u; } c;
  c.h[0] = (__bf16)a; c.h[1] = (__bf16)b;
  return c.u;
}
__device__ __forceinline__ unsigned short f2bf(float x) {
  union { __bf16 h; unsigned short s; } c; c.h = (__bf16)x; return c.s;
}
// fast sigmoid/tanh: v_exp + v_rcp (validated: v11/R6 bench passed absmax 0.0078)
__device__ __forceinline__ float fsig(float x) {
  return __builtin_amdgcn_rcpf(1.f + __expf(-x));
}
__device__ __forceinline__ float ftanh_f(float x) {
  float e = __expf(2.f * x);
  return 1.f - 2.f * __builtin_amdgcn_rcpf(e + 1.f);
}

// ---------------- conv1 v2: slab-staged bf16 MFMA, no im2col ----------------
__global__ __launch_bounds__(256, 2) void conv1_mfma(const float* __restrict__ x,
        const float* __restrict__ w, const float* __restrict__ bias,
        unsigned short* __restrict__ out) {
  __shared__ __align__(16) unsigned short img[4*64*140];   // 71.7 KB
  const int tid  = threadIdx.x;
  const int lane = tid & 63;
  const int wv   = tid >> 6;
  const int n    = blockIdx.x >> 1;
  const int half = blockIdx.x & 1;
  const int y0   = half * 60;
  {
    #pragma unroll
    for (int it = 0; it < 31; ++it) {
      int i  = it*256 + tid;          // [0, 4*64*31)
      int c  = i / 1984;
      int r  = i - c*1984;
      int y  = r / 31;
      int xq = r - y*31;
      const float4 f = *(const float4*)(x + ((size_t)(n*4 + c)*124 + (y0 + y))*124 + xq*4);
      uint2 v; v.x = pack_bf2(f.x, f.y); v.y = pack_bf2(f.z, f.w);
      *(uint2*)&img[(c*64 + y)*140 + xq*4] = v;
    }
  }
  bf16x8_t wfr[2][8];
  {
    int m = lane & 15, q = lane >> 4;
    #pragma unroll
    for (int tt = 0; tt < 2; ++tt) {
      const float* wrow = w + (size_t)(tt*16 + m)*256 + q*8;
      #pragma unroll
      for (int ks = 0; ks < 8; ++ks) {
        float4 f0 = *(const float4*)(wrow + ks*32);
        float4 f1 = *(const float4*)(wrow + ks*32 + 4);
        bf16x8_t v;
        v[0]=(__bf16)f0.x; v[1]=(__bf16)f0.y; v[2]=(__bf16)f0.z; v[3]=(__bf16)f0.w;
        v[4]=(__bf16)f1.x; v[5]=(__bf16)f1.y; v[6]=(__bf16)f1.z; v[7]=(__bf16)f1.w;
        wfr[tt][ks] = v;
      }
    }
  }
  __syncthreads();
  const int m = lane & 15, q = lane >> 4;
  int rb[8];
  #pragma unroll
  for (int ks = 0; ks < 8; ++ks) {
    int kk = ks*32 + q*8;
    rb[ks] = (kk >> 6)*64 + ((kk >> 3) & 7);
  }
  const float sc = 1.0f / 255.0f;
  for (int tile = wv; tile < 29; tile += 4) {
    int pl = tile*16 + m;
    int ok = pl < 450;
    if (!ok) pl = 449;
    int t = pl / 30, opx = pl - t*30;
    int t4 = t*4, opx4 = opx*4;
    f32x4_t acc0 = {0.f,0.f,0.f,0.f}, acc1 = {0.f,0.f,0.f,0.f};
    #pragma unroll
    for (int ks = 0; ks < 8; ++ks) {
      const unsigned short* p = &img[(rb[ks] + t4)*140 + opx4];
      union { bf16x8_t v; uint2 u[2]; } fb;
      fb.u[0] = *(const uint2*)p;
      fb.u[1] = *(const uint2*)(p + 4);
      acc0 = __builtin_amdgcn_mfma_f32_16x16x32_bf16(wfr[0][ks], fb.v, acc0, 0, 0, 0);
      acc1 = __builtin_amdgcn_mfma_f32_16x16x32_bf16(wfr[1][ks], fb.v, acc1, 0, 0, 0);
    }
    if (ok) {
      int opy = half*15 + t;
      size_t obase = (size_t)n*32*900 + opy*30 + opx;
      #pragma unroll
      for (int rg = 0; rg < 4; ++rg) {
        int oc0 = q*4 + rg;
        out[obase + (size_t)oc0*900]      = f2bf(fmaxf(acc0[rg]*sc + bias[oc0], 0.f));
        out[obase + (size_t)(oc0+16)*900] = f2bf(fmaxf(acc1[rg]*sc + bias[oc0+16], 0.f));
      }
    }
  }
}

// ---------------- conv2 v2: full-image LDS staging, bf16 output ----------------
__global__ __launch_bounds__(256, 2) void conv2_mfma(const unsigned short* __restrict__ in,
        const float* __restrict__ w, const float* __restrict__ bias,
        unsigned short* __restrict__ out) {
  __shared__ __align__(16) unsigned short img[28800];   // [c][y][x] linear, 57.6 KB
  const int tid  = threadIdx.x;
  const int lane = tid & 63;
  const int wv   = tid >> 6;
  const int n    = blockIdx.x;
  {
    const uint4* src = (const uint4*)(in + (size_t)n*28800);
    uint4* dst = (uint4*)img;
    #pragma unroll
    for (int j = 0; j < 15; ++j) {
      int s = j*256 + tid;
      if (s < 3600) dst[s] = src[s];
    }
  }
  bf16x8_t wfr[16];
  {
    int m = lane & 15, q = lane >> 4;
    const float* wrow = w + (size_t)(wv*16 + m)*512 + q*8;
    #pragma unroll
    for (int ks = 0; ks < 16; ++ks) {
      float4 f0 = *(const float4*)(wrow + ks*32);
      float4 f1 = *(const float4*)(wrow + ks*32 + 4);
      bf16x8_t v;
      v[0] = (__bf16)f0.x; v[1] = (__bf16)f0.y; v[2] = (__bf16)f0.z; v[3] = (__bf16)f0.w;
      v[4] = (__bf16)f1.x; v[5] = (__bf16)f1.y; v[6] = (__bf16)f1.z; v[7] = (__bf16)f1.w;
      wfr[ks] = v;
    }
  }
  __syncthreads();
  const int m  = lane & 15;
  const int qq = lane >> 4;
  const int cl  = qq >> 1;            // channel offset within 2-ch k-step
  const int ky0 = (qq & 1) * 2;       // row offset
  float b4[4];
  #pragma unroll
  for (int rg = 0; rg < 4; ++rg) b4[rg] = bias[wv*16 + qq*4 + rg];
  for (int tile = 0; tile < 13; ++tile) {
    int px = tile*16 + m;
    int valid = px < 196;
    int pc = valid ? px : 195;
    int oy = pc / 14, ox = pc % 14;
    const unsigned short* pb = &img[((cl*30) + oy*2 + ky0)*30 + ox*2];
    f32x4_t acc = {0.f, 0.f, 0.f, 0.f};
    #pragma unroll
    for (int ks = 0; ks < 16; ++ks) {
      const unsigned short* p0 = pb + ks*1800;    // channel 2*ks + cl
      union { bf16x8_t v; unsigned int u[4]; } fb;
      fb.u[0] = *(const unsigned int*)(p0);
      fb.u[1] = *(const unsigned int*)(p0 + 2);
      fb.u[2] = *(const unsigned int*)(p0 + 30);
      fb.u[3] = *(const unsigned int*)(p0 + 32);
      acc = __builtin_amdgcn_mfma_f32_16x16x32_bf16(wfr[ks], fb.v, acc, 0, 0, 0);
    }
    if (valid) {
      #pragma unroll
      for (int rg = 0; rg < 4; ++rg) {
        int oc = wv*16 + qq*4 + rg;
        out[((size_t)n*64 + oc)*196 + px] = f2bf(fmaxf(acc[rg] + b4[rg], 0.f));
      }
    }
  }
}

// ---------------- conv3 v2: bf16 MFMA, channel-last LDS image ----------------
__global__ __launch_bounds__(256) void conv3_mfma(const unsigned short* __restrict__ in,
        const float* __restrict__ w, const float* __restrict__ bias,
        unsigned short* __restrict__ out) {
  __shared__ __align__(16) unsigned short img[196*72];   // 27.6 KB
  const int tid  = threadIdx.x;
  const int lane = tid & 63;
  const int wv   = tid >> 6;
  const int n    = blockIdx.x;
  {
    const unsigned short* src = in + (size_t)n*12544;     // [c][196]
    for (int i = tid; i < 3136; i += 256) {
      int c = i / 49, j = i - c*49;
      uint2 v = *(const uint2*)(src + c*196 + j*4);
      int px = j*4;
      img[(px+0)*72 + c] = (unsigned short)(v.x);
      img[(px+1)*72 + c] = (unsigned short)(v.x >> 16);
      img[(px+2)*72 + c] = (unsigned short)(v.y);
      img[(px+3)*72 + c] = (unsigned short)(v.y >> 16);
    }
  }
  // weights -> A-frags: k = ks*32 + q*8 + e ; g = ks>>1, c = (ks&1)*32 + q*8 + e
  bf16x8_t wfr[2][18];
  {
    int m = lane & 15, q = lane >> 4;
    #pragma unroll
    for (int tt = 0; tt < 2; ++tt) {
      const float* wrow = w + (size_t)(tt*16 + m)*576;
      #pragma unroll
      for (int ks = 0; ks < 18; ++ks) {
        int g = ks >> 1;
        int c0 = (ks & 1)*32 + q*8;
        bf16x8_t v;
        #pragma unroll
        for (int e = 0; e < 8; ++e) v[e] = (__bf16)wrow[(c0 + e)*9 + g];
        wfr[tt][ks] = v;
      }
    }
  }
  __syncthreads();
  const int m = lane & 15, q = lane >> 4;
  for (int tile = wv; tile < 9; tile += 4) {
    int px = tile*16 + m;                 // 0..143 always valid
    int oy = px / 12, ox = px % 12;
    f32x4_t a0 = {0.f,0.f,0.f,0.f}, a1 = {0.f,0.f,0.f,0.f};
    #pragma unroll
    for (int ks = 0; ks < 18; ++ks) {
      int g = ks >> 1, ky = g / 3, kx = g % 3;
      int c0 = (ks & 1)*32 + q*8;
      const unsigned short* p = &img[((oy + ky)*14 + ox + kx)*72 + c0];
      union { bf16x8_t v; uint4 u; } fb;
      fb.u = *(const uint4*)p;
      a0 = __builtin_amdgcn_mfma_f32_16x16x32_bf16(wfr[0][ks], fb.v, a0, 0, 0, 0);
      a1 = __builtin_amdgcn_mfma_f32_16x16x32_bf16(wfr[1][ks], fb.v, a1, 0, 0, 0);
    }
    #pragma unroll
    for (int rg = 0; rg < 4; ++rg) {
      int oc = q*4 + rg;
      out[((size_t)n*32 + oc)*144 + px]      = f2bf(fmaxf(a0[rg] + bias[oc], 0.f));
      out[((size_t)n*32 + oc + 16)*144 + px] = f2bf(fmaxf(a1[rg] + bias[oc + 16], 0.f));
    }
  }
}

// ---------------- W fp32 -> bf16 one-shot convert (+ flags zero) ----------------
__global__ __launch_bounds__(256) void cvt_w_k(const float* __restrict__ w,
        unsigned short* __restrict__ o, int* __restrict__ flags) {
  if (blockIdx.x == 0) ((int4*)flags)[threadIdx.x] = make_int4(0, 0, 0, 0);  // 4 KB
  int i = (blockIdx.x*256 + threadIdx.x) * 8;
  float4 f0 = *(const float4*)(w + i);
  float4 f1 = *(const float4*)(w + i + 4);
  uint4 v;
  v.x = pack_bf2(f0.x, f0.y); v.y = pack_bf2(f0.z, f0.w);
  v.z = pack_bf2(f1.x, f1.y); v.w = pack_bf2(f1.z, f1.w);
  *(uint4*)(o + i) = v;
}

// ---------------- fc: bf16 MFMA GEMM, split-K x4 -> fp32 partials ----------------
__global__ __launch_bounds__(256) void fc_mfma(const unsigned short* __restrict__ A,
        const unsigned short* __restrict__ Wb, float* __restrict__ part) {
  __shared__ __align__(16) unsigned short As[64*72];
  __shared__ __align__(16) unsigned short Wsm[64*72];
  const int tid  = threadIdx.x;
  const int lane = tid & 63;
  const int wv   = tid >> 6;
  const int m0 = blockIdx.y * 64, n0 = blockIdx.x * 64;
  const int kz = blockIdx.z * 1152;
  const int r  = tid >> 2;
  const int cq = (tid & 3) * 16;
  f32x4_t acc[4] = {{0,0,0,0},{0,0,0,0},{0,0,0,0},{0,0,0,0}};
  for (int k0 = 0; k0 < 1152; k0 += 64) {
    __syncthreads();
    {
      const uint4* src = (const uint4*)(A + (size_t)(m0 + r)*4608 + kz + k0 + cq);
      uint4 a0 = src[0], a1 = src[1];
      *(uint4*)&As[r*72 + cq]     = a0;
      *(uint4*)&As[r*72 + cq + 8] = a1;
    }
    {
      const uint4* src = (const uint4*)(Wb + (size_t)(n0 + r)*4608 + kz + k0 + cq);
      uint4 w0 = src[0], w1 = src[1];
      *(uint4*)&Wsm[r*72 + cq]     = w0;
      *(uint4*)&Wsm[r*72 + cq + 8] = w1;
    }
    __syncthreads();
    #pragma unroll
    for (int kk = 0; kk < 2; ++kk) {
      union { bf16x8_t v; uint4 u; } bf;
      bf.u = *(const uint4*)&As[(wv*16 + (lane & 15))*72 + kk*32 + (lane >> 4)*8];
      #pragma unroll
      for (int tt = 0; tt < 4; ++tt) {
        union { bf16x8_t v; uint4 u; } af;
        af.u = *(const uint4*)&Wsm[(tt*16 + (lane & 15))*72 + kk*32 + (lane >> 4)*8];
        acc[tt] = __builtin_amdgcn_mfma_f32_16x16x32_bf16(af.v, bf.v, acc[tt], 0, 0, 0);
      }
    }
  }
  {
    int m = m0 + wv*16 + (lane & 15);
    int q4 = lane >> 4;
    float* dst = part + (size_t)blockIdx.z*262144;
    #pragma unroll
    for (int tt = 0; tt < 4; ++tt) {
      #pragma unroll
      for (int rg = 0; rg < 4; ++rg) {
        int n = n0 + tt*16 + q4*4 + rg;
        dst[(size_t)m*512 + n] = acc[tt][rg];
      }
    }
  }
}

// ---------------- fc reduce: xs = relu(sum_z part + bias) ----------------
__global__ __launch_bounds__(256) void fc_red(const float* __restrict__ part,
        const float* __restrict__ bias, float* __restrict__ C) {
  int idx = blockIdx.x*256 + threadIdx.x;      // 0..65535 float4s
  int nq = idx & 127;
  const float4* p = (const float4*)part;
  float4 s0 = p[idx];
  float4 s1 = p[65536 + idx];
  float4 s2 = p[131072 + idx];
  float4 s3 = p[196608 + idx];
  float4 b = *(const float4*)(bias + nq*4);
  float4 r;
  r.x = fmaxf(s0.x + s1.x + s2.x + s3.x + b.x, 0.f);
  r.y = fmaxf(s0.y + s1.y + s2.y + s3.y + b.y, 0.f);
  r.z = fmaxf(s0.z + s1.z + s2.z + s3.z + b.z, 0.f);
  r.w = fmaxf(s0.w + s1.w + s2.w + s3.w + b.w, 0.f);
  ((float4*)C)[idx] = r;
}

// ---------------- gi: bf16x2 split-precision MFMA GEMM ----------------
__global__ __launch_bounds__(256) void gi_mfma(const float* __restrict__ A,
        const float* __restrict__ W, const float* __restrict__ bias,
        float* __restrict__ C) {
  __shared__ __align__(16) unsigned short Ash[64*72], Asl[64*72];
  __shared__ __align__(16) unsigned short Wsh[64*72], Wsl[64*72];
  const int tid  = threadIdx.x;
  const int lane = tid & 63;
  const int wv   = tid >> 6;
  const int m0 = blockIdx.y * 64, n0 = blockIdx.x * 64;
  const int r  = tid >> 2;
  const int cq = (tid & 3) * 16;
  f32x4_t acc[4] = {{0,0,0,0},{0,0,0,0},{0,0,0,0},{0,0,0,0}};
  for (int k0 = 0; k0 < 512; k0 += 64) {
    __syncthreads();
    #pragma unroll
    for (int op = 0; op < 2; ++op) {
      const float* src = (op ? W + (size_t)(n0 + r)*512 : A + (size_t)(m0 + r)*512) + k0 + cq;
      unsigned short* dh = (op ? Wsh : Ash) + r*72 + cq;
      unsigned short* dl = (op ? Wsl : Asl) + r*72 + cq;
      #pragma unroll
      for (int hb = 0; hb < 2; ++hb) {
        float4 f0 = *(const float4*)(src + hb*8);
        float4 f1 = *(const float4*)(src + hb*8 + 4);
        float v[8] = {f0.x,f0.y,f0.z,f0.w,f1.x,f1.y,f1.z,f1.w};
        uint4 vh, vl;
        unsigned int* ph = (unsigned int*)&vh;
        unsigned int* pl = (unsigned int*)&vl;
        #pragma unroll
        for (int e = 0; e < 4; ++e) {
          float a = v[e*2], b = v[e*2+1];
          __bf16 ah = (__bf16)a, bh = (__bf16)b;
          union { __bf16 h[2]; unsigned int u; } ch, clo;
          ch.h[0] = ah; ch.h[1] = bh;
          clo.h[0] = (__bf16)(a - (float)ah); clo.h[1] = (__bf16)(b - (float)bh);
          ph[e] = ch.u; pl[e] = clo.u;
        }
        *(uint4*)(dh + hb*8) = vh;
        *(uint4*)(dl + hb*8) = vl;
      }
    }
    __syncthreads();
    #pragma unroll
    for (int kk = 0; kk < 2; ++kk) {
      int boff = (wv*16 + (lane & 15))*72 + kk*32 + (lane >> 4)*8;
      union { bf16x8_t v; uint4 u; } bh, bl;
      bh.u = *(const uint4*)&Ash[boff];
      bl.u = *(const uint4*)&Asl[boff];
      #pragma unroll
      for (int tt = 0; tt < 4; ++tt) {
        int aoff = (tt*16 + (lane & 15))*72 + kk*32 + (lane >> 4)*8;
        union { bf16x8_t v; uint4 u; } ah, al;
        ah.u = *(const uint4*)&Wsh[aoff];
        al.u = *(const uint4*)&Wsl[aoff];
        acc[tt] = __builtin_amdgcn_mfma_f32_16x16x32_bf16(ah.v, bh.v, acc[tt], 0, 0, 0);
        acc[tt] = __builtin_amdgcn_mfma_f32_16x16x32_bf16(ah.v, bl.v, acc[tt], 0, 0, 0);
        acc[tt] = __builtin_amdgcn_mfma_f32_16x16x32_bf16(al.v, bh.v, acc[tt], 0, 0, 0);
      }
    }
  }
  {
    int m = m0 + wv*16 + (lane & 15);
    int q4 = lane >> 4;
    #pragma unroll
    for (int tt = 0; tt < 4; ++tt) {
      #pragma unroll
      for (int rg = 0; rg < 4; ++rg) {
        int n = n0 + tt*16 + q4*4 + rg;
        C[(size_t)m*1536 + n] = acc[tt][rg] + bias[n];
      }
    }
  }
}

// ---------------- GRU persistent kernel v9 (FINAL: verified 122.5 us, R4/R5) ----------------
#define GRU_NB 8
__global__ __launch_bounds__(512) void gru_k(const float* __restrict__ gi, const float* __restrict__ states,
    const float* __restrict__ masks, const float* __restrict__ w_hh, const float* __restrict__ b_hh,
    float* __restrict__ outs, unsigned int* __restrict__ hbuf, int* __restrict__ flags,
    float* __restrict__ states_out) {
  __shared__ __align__(16) unsigned short hbf[16*520];
  __shared__ float hp_s[16*64];
  __shared__ float gh_s[192*17];
  __shared__ float bhs[192];
  __shared__ float mask_s[512];
  const int b    = blockIdx.x;
  const int tid  = threadIdx.x;
  const int lane = tid & 63;
  const int wv   = tid >> 6;          // 0..7
  const int jbase = b * 64;
  const int gn = tid >> 5;            // batch row 0..15
  const int gj = (tid & 31) * 2;      // adjacent j-pair 0..62

  mask_s[tid < 512 ? tid : 0] = masks[tid < 512 ? tid : 0];
  if (tid < 192) bhs[tid] = b_hh[(tid >> 6)*512 + jbase + (tid & 63)];

  bf16x8_t wfr[2][16];
  {
    int r = lane & 15, q = lane >> 4;
    #pragma unroll
    for (int ti = 0; ti < 2; ++ti) {
      int tt = wv + ti*8;
      if (tt < 12) {
        int g = tt >> 2, jt = (tt & 3) * 16;
        const float* wrow = w_hh + (size_t)(g*512 + jbase + jt + r)*512 + q*8;
        #pragma unroll
        for (int ks = 0; ks < 16; ++ks) {
          float4 f0 = *(const float4*)(wrow + ks*32);
          float4 f1 = *(const float4*)(wrow + ks*32 + 4);
          bf16x8_t v;
          v[0] = (__bf16)f0.x; v[1] = (__bf16)f0.y; v[2] = (__bf16)f0.z; v[3] = (__bf16)f0.w;
          v[4] = (__bf16)f1.x; v[5] = (__bf16)f1.y; v[6] = (__bf16)f1.z; v[7] = (__bf16)f1.w;
          wfr[ti][ks] = v;
        }
      }
    }
  }
  __syncthreads();

  for (int t = 0; t < 32; ++t) {
    const float* gip = gi + (size_t)(t*16 + gn)*1536 + jbase + gj;
    float2 giR = *(const float2*)(gip);
    float2 giZ = *(const float2*)(gip + 512);
    float2 giN = *(const float2*)(gip + 1024);

    if (t == 0) {
      for (int i = tid; i < 4096; i += 512) {
        int nn = i >> 8, kp = (i & 255) * 2;
        float m = mask_s[nn];
        float f0 = states[nn*512 + kp], f1 = states[nn*512 + kp + 1];
        *(unsigned int*)&hbf[nn*520 + kp] = pack_bf2(f0*m, f1*m);
      }
      {
        float m0 = mask_s[gn];
        hp_s[gn*64 + gj]     = states[gn*512 + jbase + gj] * m0;
        hp_s[gn*64 + gj + 1] = states[gn*512 + jbase + gj + 1] * m0;
      }
      __syncthreads();
    } else {
      {
        int done = 0;
        while (!done) {
          int ok = 1;
          if (lane < 8) {
            int v = __hip_atomic_load(&flags[lane*16], __ATOMIC_RELAXED, __HIP_MEMORY_SCOPE_AGENT);
            ok = (v >= t);
          }
          done = __all(ok);
          if (!done) __builtin_amdgcn_s_sleep(1);
        }
      }
      {
        const unsigned long long* hsrc =
            (const unsigned long long*)(hbuf + (t & 1)*4096);
        #pragma unroll
        for (int idx = tid; idx < 1792; idx += 512) {
          int s  = idx >> 8;                // 0..6
          int p  = s + (s >= b);            // skip own slice
          int rem = idx & 255;
          int nn = rem >> 4;
          int jw = rem & 15;                // u64 word within 64-col row
          unsigned long long u = __hip_atomic_load(hsrc + p*256 + nn*16 + jw,
                                 __ATOMIC_RELAXED, __HIP_MEMORY_SCOPE_AGENT);
          *(unsigned long long*)&hbf[nn*520 + p*64 + jw*4] = u;
        }
      }
      __syncthreads();
    }

    // MFMA: gh = w_hh(slice) * h
    {
      int r = lane & 15, q = lane >> 4;
      const unsigned short* hrow = &hbf[r*520 + q*8];
      #pragma unroll
      for (int ti = 0; ti < 2; ++ti) {
        int tt = wv + ti*8;
        if (tt < 12) {
          f32x4_t acc = {0.f, 0.f, 0.f, 0.f};
          #pragma unroll
          for (int ks = 0; ks < 16; ++ks) {
            union { bf16x8_t v; uint4 u; } fb;
            fb.u = *(const uint4*)(hrow + ks*32);
            acc = __builtin_amdgcn_mfma_f32_16x16x32_bf16(wfr[ti][ks], fb.v, acc, 0, 0, 0);
          }
          int g = tt >> 2, jt = (tt & 3) * 16;
          #pragma unroll
          for (int rg = 0; rg < 4; ++rg)
            gh_s[(g*64 + jt + q*4 + rg)*17 + r] = acc[rg];
        }
      }
    }
    __syncthreads();

    // gates: 2 adjacent j per thread, publish -> barrier -> flag -> cold stores
    {
      float ghr0 = gh_s[(gj    )*17 + gn] + bhs[gj];
      float ghr1 = gh_s[(gj + 1)*17 + gn] + bhs[gj + 1];
      float ghz0 = gh_s[(64 + gj)*17 + gn] + bhs[64 + gj];
      float ghz1 = gh_s[(65 + gj)*17 + gn] + bhs[65 + gj];
      float ghn0 = gh_s[(128 + gj)*17 + gn] + bhs[128 + gj];
      float ghn1 = gh_s[(129 + gj)*17 + gn] + bhs[129 + gj];
      float r0 = fsig(giR.x + ghr0);
      float r1 = fsig(giR.y + ghr1);
      float z0 = fsig(giZ.x + ghz0);
      float z1 = fsig(giZ.y + ghz1);
      float n0 = ftanh_f(giN.x + r0*ghn0);
      float n1 = ftanh_f(giN.y + r1*ghn1);
      float hp0 = hp_s[gn*64 + gj];
      float hp1 = hp_s[gn*64 + gj + 1];
      float hn0 = (1.f - z0)*n0 + z0*hp0;
      float hn1 = (1.f - z1)*n1 + z1*hp1;
      float mnext = (t < 31) ? mask_s[(t+1)*16 + gn] : 0.f;
      float hm0 = hn0 * mnext, hm1 = hn1 * mnext;
      if (t < 31) {
        __hip_atomic_store(hbuf + ((t+1)&1)*4096 + b*512 + gn*32 + (gj >> 1),
                           pack_bf2(hm0, hm1), __ATOMIC_RELAXED, __HIP_MEMORY_SCOPE_AGENT);
      }
      __syncthreads();   // drains all threads' publishes (vmcnt(0)) before flag
      if (t < 31) {
        if (tid == 0)
          __hip_atomic_store(&flags[b*16], t + 1, __ATOMIC_RELAXED, __HIP_MEMORY_SCOPE_AGENT);
        *(float2*)&outs[(size_t)(t*16 + gn)*512 + jbase + gj] = make_float2(hn0, hn1);
        hp_s[gn*64 + gj]     = hm0;
        hp_s[gn*64 + gj + 1] = hm1;
        *(unsigned int*)&hbf[gn*520 + jbase + gj] = pack_bf2(hm0, hm1);
      } else {
        *(float2*)&outs[(size_t)(t*16 + gn)*512 + jbase + gj] = make_float2(hn0, hn1);
        *(float2*)&states_out[gn*512 + jbase + gj] = make_float2(hn0, hn1);
      }
    }
  }
}

// ---------------- heads ----------------
__global__ __launch_bounds__(256) void heads_k(const float* __restrict__ xs, const int* __restrict__ action,
    const float* __restrict__ aw, const float* __restrict__ ab,
    const float* __restrict__ cw, const float* __restrict__ cb, float* __restrict__ out) {
  int row  = blockIdx.x * 4 + (threadIdx.x >> 6);
  int lane = threadIdx.x & 63;
  const float* xr = xs + (size_t)row * 512;
  float acc[7];
  #pragma unroll
  for (int a = 0; a < 7; ++a) acc[a] = 0.f;
  #pragma unroll
  for (int kb = 0; kb < 8; ++kb) {
    int k = kb*64 + lane;
    float xv = xr[k];
    #pragma unroll
    for (int a = 0; a < 6; ++a) acc[a] += xv * aw[a*512 + k];
    acc[6] += xv * cw[k];
  }
  #pragma unroll
  for (int off = 32; off > 0; off >>= 1) {
    #pragma unroll
    for (int a = 0; a < 7; ++a) acc[a] += __shfl_down(acc[a], off);
  }
  if (lane == 0) {
    float lg[6];
    #pragma unroll
    for (int a = 0; a < 6; ++a) lg[a] = acc[a] + ab[a];
    float mx = lg[0];
    #pragma unroll
    for (int a = 1; a < 6; ++a) mx = fmaxf(mx, lg[a]);
    float se = 0.f;
    #pragma unroll
    for (int a = 0; a < 6; ++a) se += expf(lg[a] - mx);
    float lse = mx + logf(se);
    float ent = 0.f;
    #pragma unroll
    for (int a = 0; a < 6; ++a) { float lp = lg[a] - lse; ent -= expf(lp)*lp; }
    int ai = action[row];
    out[row]        = acc[6] + cb[0];
    out[512  + row] = lg[ai] - lse;
    out[1024 + row] = ent;
  }
}

extern "C" void kernel_launch(void* const* d_in, const int* in_sizes, int n_in,
                              void* d_out, int out_size, void* d_ws, size_t ws_size,
                              hipStream_t stream) {
  const float* x      = (const float*)d_in[0];
  const float* states = (const float*)d_in[1];
  const float* masks  = (const float*)d_in[2];
  const int*   action = (const int*)d_in[3];
  const float* c1w = (const float*)d_in[4];
  const float* c1b = (const float*)d_in[5];
  const float* c2w = (const float*)d_in[6];
  const float* c2b = (const float*)d_in[7];
  const float* c3w = (const float*)d_in[8];
  const float* c3b = (const float*)d_in[9];
  const float* fcw = (const float*)d_in[10];
  const float* fcb = (const float*)d_in[11];
  const float* wih = (const float*)d_in[12];
  const float* whh = (const float*)d_in[13];
  const float* bih = (const float*)d_in[14];
  const float* bhh = (const float*)d_in[15];
  const float* aw  = (const float*)d_in[16];
  const float* ab  = (const float*)d_in[17];
  const float* cw  = (const float*)d_in[18];
  const float* cb  = (const float*)d_in[19];
  (void)in_sizes; (void)n_in; (void)out_size; (void)ws_size;

  float* ws = (float*)d_ws;
  // Workspace map (float offsets):
  //   [0, 7372800)        o1b conv1 out bf16 (29.5 MB)  -> later o3b (4.7 MB)
  //   [2359296, 2621440)  xs fp32
  //   [2621440, 3407872)  gibuf
  //   [3407872, 3670016)  outs
  //   [3670016, 3686400)  hbuf ; [3686400, +1024 ints) flags
  //   [7372800, 8552448)  wbf: fc W bf16 (4.7 MB)
  //   [8552448, 9601024)  fc partials 4 x 512 x 512 fp32 (4 MB)
  //   [14745600, ...)     o2b conv2 out bf16 (12.9 MB)
  unsigned short* o1b = (unsigned short*)ws;
  unsigned short* o2b = (unsigned short*)(ws + 14745600);
  unsigned short* o3b = (unsigned short*)ws;
  float* xs    = ws + 2359296;
  float* gibuf = ws + 2621440;
  float* outs  = ws + 3407872;
  unsigned int* hbuf = (unsigned int*)(ws + 3670016);
  int*   flags = (int*)(ws + 3686400);
  unsigned short* wbf = (unsigned short*)(ws + 7372800);
  float* fcpart = ws + 8552448;
  float* out   = (float*)d_out;

  cvt_w_k<<<1152, 256, 0, stream>>>(fcw, wbf, flags);
  conv1_mfma<<<1024, 256, 0, stream>>>(x, c1w, c1b, o1b);
  conv2_mfma<<<512, 256, 0, stream>>>(o1b, c2w, c2b, o2b);
  conv3_mfma<<<512, 256, 0, stream>>>(o2b, c3w, c3b, o3b);
  fc_mfma<<<dim3(8, 8, 4), 256, 0, stream>>>(o3b, wbf, fcpart);
  fc_red<<<256, 256, 0, stream>>>(fcpart, fcb, xs);
  gi_mfma<<<dim3(24, 8), 256, 0, stream>>>(xs, wih, bih, gibuf);
  gru_k<<<GRU_NB, 512, 0, stream>>>(gibuf, states, masks, whh, bhh, outs, hbuf, flags, out + 1536);
  heads_k<<<128, 256, 0, stream>>>(outs, action, aw, ab, cw, cb, out);
}